// Round 2
// baseline (1055.211 us; speedup 1.0000x reference)
//
#include <hip/hip_runtime.h>

#define B_ 2
#define H_ 16
#define S_ 2048
#define D_ 64
#define SPLIT1 8   // key-split for sum kernel
#define SPLIT2 4   // key-split for main kernel

typedef short v8s __attribute__((ext_vector_type(8)));   // 8 bf16 (bit patterns) = 4 VGPRs
typedef float v4f __attribute__((ext_vector_type(4)));
typedef unsigned short u16;
typedef unsigned int   u32;
typedef unsigned long long u64;

// pack two fp32 -> two bf16 (round-half-up: +0x8000 then take high 16 via v_perm)
__device__ __forceinline__ u32 pk2(float a, float b) {
    u32 ua = __float_as_uint(a) + 0x8000u;
    u32 ub = __float_as_uint(b) + 0x8000u;
    return __builtin_amdgcn_perm(ub, ua, 0x07060302u);  // lo16=hi(ua), hi16=hi(ub)
}

// load 8 consecutive fp32, scale, convert to bf16x8 fragment
__device__ __forceinline__ v8s cvt8(const float* __restrict__ p, float s) {
    float4 x = ((const float4*)p)[0];
    float4 y = ((const float4*)p)[1];
    union { u32 u[4]; v8s v; } r;
    r.u[0] = pk2(x.x * s, x.y * s);
    r.u[1] = pk2(x.z * s, x.w * s);
    r.u[2] = pk2(y.x * s, y.y * s);
    r.u[3] = pk2(y.z * s, y.w * s);
    return r.v;
}

// ---------------- prep kernels ----------------

__global__ void zero_k(float4* __restrict__ p, int n4) {
    int i = blockIdx.x * 256 + threadIdx.x;
    if (i < n4) p[i] = float4{0.f, 0.f, 0.f, 0.f};
}

// fp32 -> bf16, 8 elems/thread (K matrix)
__global__ void cvt_bf16_k(const float* __restrict__ src, u16* __restrict__ dst) {
    size_t i = (size_t)blockIdx.x * blockDim.x + threadIdx.x;
    const float* p = src + i * 8;
    float4 a = ((const float4*)p)[0], b = ((const float4*)p)[1];
    uint4 o;
    o.x = pk2(a.x, a.y); o.y = pk2(a.z, a.w);
    o.z = pk2(b.x, b.y); o.w = pk2(b.z, b.w);
    ((uint4*)dst)[i] = o;
}

// V[b,h,s,d] fp32 -> Vt[b,h,d,s] bf16 (64x64 tiles through LDS)
__global__ void vtrans_k(const float* __restrict__ V, u16* __restrict__ Vt) {
    __shared__ u16 t[64][66];
    const int bh = blockIdx.y, s0 = blockIdx.x * 64;
    const int tid = threadIdx.x;
    {
        const int r = tid >> 2, c0 = (tid & 3) * 16;
        const float* p = V + ((size_t)bh * S_ + s0 + r) * D_ + c0;
        float4 f0 = ((const float4*)p)[0], f1 = ((const float4*)p)[1];
        float4 f2 = ((const float4*)p)[2], f3 = ((const float4*)p)[3];
        u32* tw = (u32*)&t[r][c0];
        tw[0] = pk2(f0.x, f0.y); tw[1] = pk2(f0.z, f0.w);
        tw[2] = pk2(f1.x, f1.y); tw[3] = pk2(f1.z, f1.w);
        tw[4] = pk2(f2.x, f2.y); tw[5] = pk2(f2.z, f2.w);
        tw[6] = pk2(f3.x, f3.y); tw[7] = pk2(f3.z, f3.w);
    }
    __syncthreads();
    {
        const int d = tid >> 2, sc = (tid & 3) * 16;
        u32 o[8];
        #pragma unroll
        for (int u = 0; u < 8; ++u)
            o[u] = (u32)t[sc + 2 * u][d] | ((u32)t[sc + 2 * u + 1][d] << 16);
        u16* q = Vt + ((size_t)bh * D_ + d) * S_ + s0 + sc;
        ((uint4*)q)[0] = make_uint4(o[0], o[1], o[2], o[3]);
        ((uint4*)q)[1] = make_uint4(o[4], o[5], o[6], o[7]);
    }
}

// mask int32 -> bitmask (1 bit/elem)
__global__ void mbits_k(const int* __restrict__ mask, u64* __restrict__ mb) {
    size_t i = (size_t)blockIdx.x * blockDim.x + threadIdx.x;
    u64 bal = __ballot(mask[i] != 0);
    if ((threadIdx.x & 63) == 0) mb[i >> 6] = bal;
}

// ---------------- kernel 1: row sums of masked exp (split-K) ----------------
__global__ __launch_bounds__(256, 8)
void sum_k(const float* __restrict__ Q, const u16* __restrict__ Kb,
           const u32* __restrict__ mbits, float* __restrict__ sumbuf)
{
    const int tid = threadIdx.x;
    const int w = tid >> 6, lane = tid & 63;
    const int n = lane & 15, g = lane >> 4;
    const int qb = blockIdx.x >> 3, sp = blockIdx.x & 7;
    const int h = blockIdx.y, b = blockIdx.z;
    const int bh = b * H_ + h;
    const int q0 = qb * 64 + w * 16;
    const int kbeg = sp * (S_ / SPLIT1);

    const float* qrow = Q + ((size_t)bh * S_ + q0 + n) * D_;
    const v8s aq0 = cvt8(qrow + g * 8, 0.125f);
    const v8s aq1 = cvt8(qrow + 32 + g * 8, 0.125f);

    const u16* kbbase = Kb + ((size_t)bh * S_ + n) * D_ + g * 8;
    const u32* mbase = mbits + ((size_t)b * S_ + q0 + g * 4) * (S_ / 32);

    v4f sum = {0.f, 0.f, 0.f, 0.f};
    for (int k0 = kbeg; k0 < kbeg + S_ / SPLIT1; k0 += 32) {
        v4f a0 = {0.f, 0.f, 0.f, 0.f}, a1 = {0.f, 0.f, 0.f, 0.f};
        a0 = __builtin_amdgcn_mfma_f32_16x16x32_bf16(aq0, *(const v8s*)(kbbase + (size_t)k0 * D_),        a0, 0, 0, 0);
        a0 = __builtin_amdgcn_mfma_f32_16x16x32_bf16(aq1, *(const v8s*)(kbbase + (size_t)k0 * D_ + 32),   a0, 0, 0, 0);
        a1 = __builtin_amdgcn_mfma_f32_16x16x32_bf16(aq0, *(const v8s*)(kbbase + (size_t)(k0+16) * D_),      a1, 0, 0, 0);
        a1 = __builtin_amdgcn_mfma_f32_16x16x32_bf16(aq1, *(const v8s*)(kbbase + (size_t)(k0+16) * D_ + 32), a1, 0, 0, 0);
        #pragma unroll
        for (int i = 0; i < 4; ++i) {
            u32 mw = mbase[i * (S_ / 32) + (k0 >> 5)];
            float e0 = ((mw >> n) & 1) ? __expf(a0[i]) : 0.f;
            float e1 = ((mw >> (n + 16)) & 1) ? __expf(a1[i]) : 0.f;
            sum[i] += e0 + e1;
        }
    }
    #pragma unroll
    for (int i = 0; i < 4; ++i) {
        float s = sum[i];
        s += __shfl_xor(s, 1, 64);
        s += __shfl_xor(s, 2, 64);
        s += __shfl_xor(s, 4, 64);
        s += __shfl_xor(s, 8, 64);
        if (n == i) atomicAdd(sumbuf + (size_t)bh * S_ + q0 + g * 4 + i, s);
    }
}

// ---------------- kernel 2: write P, accumulate O (split-K, atomics) ----------------
__global__ __launch_bounds__(256, 8)
void main_k(const float* __restrict__ Q, const u16* __restrict__ Kb,
            const u16* __restrict__ Vt, const u32* __restrict__ mbits,
            const float* __restrict__ sumbuf,
            float* __restrict__ out, float* __restrict__ P)
{
    __shared__ u16 ldsbuf[4][640];                   // per-wave 16 rows x 80 B
    const int tid = threadIdx.x;
    const int w = tid >> 6, lane = tid & 63;
    const int n = lane & 15, g = lane >> 4;
    const int qb = blockIdx.x >> 2, sp = blockIdx.x & 3;
    const int h = blockIdx.y, b = blockIdx.z;
    const int bh = b * H_ + h;
    const int q0 = qb * 64 + w * 16;
    const int kbeg = sp * (S_ / SPLIT2);

    const float* qrow = Q + ((size_t)bh * S_ + q0 + n) * D_;
    const v8s aq0 = cvt8(qrow + g * 8, 0.125f);
    const v8s aq1 = cvt8(qrow + 32 + g * 8, 0.125f);

    const u16* kbbase = Kb + ((size_t)bh * S_ + n) * D_ + g * 8;
    const u16* vbase  = Vt + ((size_t)bh * D_ + n) * S_ + g * 4;
    const u32* mbase  = mbits + ((size_t)b * S_ + q0 + g * 4) * (S_ / 32);

    v4f inv;
    #pragma unroll
    for (int i = 0; i < 4; ++i)
        inv[i] = 1.0f / sumbuf[(size_t)bh * S_ + q0 + g * 4 + i];

    char* ldsw = (char*)&ldsbuf[w][0];
    v4f o0 = {0.f, 0.f, 0.f, 0.f}, o1 = o0, o2 = o0, o3 = o0;

    for (int k0 = kbeg; k0 < kbeg + S_ / SPLIT2; k0 += 32) {
        v4f a0 = {0.f, 0.f, 0.f, 0.f}, a1 = {0.f, 0.f, 0.f, 0.f};
        a0 = __builtin_amdgcn_mfma_f32_16x16x32_bf16(aq0, *(const v8s*)(kbbase + (size_t)k0 * D_),        a0, 0, 0, 0);
        a0 = __builtin_amdgcn_mfma_f32_16x16x32_bf16(aq1, *(const v8s*)(kbbase + (size_t)k0 * D_ + 32),   a0, 0, 0, 0);
        a1 = __builtin_amdgcn_mfma_f32_16x16x32_bf16(aq0, *(const v8s*)(kbbase + (size_t)(k0+16) * D_),      a1, 0, 0, 0);
        a1 = __builtin_amdgcn_mfma_f32_16x16x32_bf16(aq1, *(const v8s*)(kbbase + (size_t)(k0+16) * D_ + 32), a1, 0, 0, 0);
        #pragma unroll
        for (int i = 0; i < 4; ++i) {
            u32 mw = mbase[i * (S_ / 32) + (k0 >> 5)];
            float p0 = ((mw >> n) & 1) ? __expf(a0[i]) * inv[i] : 0.f;
            float p1 = ((mw >> (n + 16)) & 1) ? __expf(a1[i]) * inv[i] : 0.f;
            *(u32*)(ldsw + (g * 4 + i) * 80 + n * 4) = pk2(p0, p1);
        }
        // A-frag of P: lane row = n, kappa block g -> 16 contiguous bytes
        union { u32 u[4]; v8s v; } ap;
        ap.v = *(const v8s*)(ldsw + n * 80 + g * 16);

        // P store from the fragment: row q0+n, keys [k0+4g, +4) lo16, [k0+16+4g, +4) hi16
        float4 plo, phi;
        plo.x = __uint_as_float(ap.u[0] << 16);  phi.x = __uint_as_float(ap.u[0] & 0xFFFF0000u);
        plo.y = __uint_as_float(ap.u[1] << 16);  phi.y = __uint_as_float(ap.u[1] & 0xFFFF0000u);
        plo.z = __uint_as_float(ap.u[2] << 16);  phi.z = __uint_as_float(ap.u[2] & 0xFFFF0000u);
        plo.w = __uint_as_float(ap.u[3] << 16);  phi.w = __uint_as_float(ap.u[3] & 0xFFFF0000u);
        float* prow = P + ((size_t)bh * S_ + q0 + n) * S_ + k0 + 4 * g;
        *(float4*)prow        = plo;
        *(float4*)(prow + 16) = phi;

        // V B-frags (kappa-interleaved) and PV MFMA
        #pragma unroll
        for (int dt = 0; dt < 4; ++dt) {
            const u16* vp = vbase + (size_t)dt * 16 * S_ + k0;
            uint2 ra = *(const uint2*)vp;
            uint2 rb = *(const uint2*)(vp + 16);
            union { u32 u[4]; v8s v; } r;
            r.u[0] = __builtin_amdgcn_perm(rb.x, ra.x, 0x05040100u);
            r.u[1] = __builtin_amdgcn_perm(rb.x, ra.x, 0x07060302u);
            r.u[2] = __builtin_amdgcn_perm(rb.y, ra.y, 0x05040100u);
            r.u[3] = __builtin_amdgcn_perm(rb.y, ra.y, 0x07060302u);
            if (dt == 0) o0 = __builtin_amdgcn_mfma_f32_16x16x32_bf16(ap.v, r.v, o0, 0, 0, 0);
            if (dt == 1) o1 = __builtin_amdgcn_mfma_f32_16x16x32_bf16(ap.v, r.v, o1, 0, 0, 0);
            if (dt == 2) o2 = __builtin_amdgcn_mfma_f32_16x16x32_bf16(ap.v, r.v, o2, 0, 0, 0);
            if (dt == 3) o3 = __builtin_amdgcn_mfma_f32_16x16x32_bf16(ap.v, r.v, o3, 0, 0, 0);
        }
    }

    float* obase = out + ((size_t)bh * S_ + q0 + g * 4) * D_ + n;
    #pragma unroll
    for (int i = 0; i < 4; ++i) {
        atomicAdd(obase + (size_t)i * D_,      o0[i]);
        atomicAdd(obase + (size_t)i * D_ + 16, o1[i]);
        atomicAdd(obase + (size_t)i * D_ + 32, o2[i]);
        atomicAdd(obase + (size_t)i * D_ + 48, o3[i]);
    }
}

// ---------------- fallback (no workspace): round-1 monolith, known-good ----------------
__global__ __launch_bounds__(256, 4)
void attn_mono(const float* __restrict__ Q, const float* __restrict__ K,
               const float* __restrict__ V, const int* __restrict__ mask,
               float* __restrict__ out, float* __restrict__ P)
{
    __shared__ u16 ldsbuf[4][640];
    const int tid = threadIdx.x;
    const int w = tid >> 6, lane = tid & 63;
    const int n = lane & 15, g = lane >> 4;
    const int qb = blockIdx.x, h = blockIdx.y, b = blockIdx.z;
    const int bh = b * H_ + h;
    const int q0 = qb * 64 + w * 16;

    const float* qrow = Q + ((size_t)bh * S_ + q0 + n) * D_;
    const v8s aq0 = cvt8(qrow + g * 8, 0.125f);
    const v8s aq1 = cvt8(qrow + 32 + g * 8, 0.125f);

    const int* mrow = mask + ((size_t)b * S_ + q0 + g * 4) * S_ + n;
    const float* kfbase = K + ((size_t)bh * S_ + n) * D_ + g * 8;

    auto loadK = [&](int key0, int dh) -> v8s {
        return cvt8(kfbase + (size_t)key0 * D_ + dh * 32, 1.0f);
    };
    auto loadM = [&](int i, int k0) -> u32 {
        u32 r = 0;
        if (mrow[(size_t)i * S_ + k0]) r |= 1u << n;
        if (mrow[(size_t)i * S_ + k0 + 16]) r |= 1u << (n + 16);
        return r;
    };
    auto loadV = [&](int k0, int dt) -> v8s {
        union { u32 u[4]; v8s v; } r;
        const float* vp = V + ((size_t)bh * S_ + k0 + g * 4) * D_ + dt * 16 + n;
        #pragma unroll
        for (int p2 = 0; p2 < 4; ++p2) {
            float fa = vp[(size_t)p2 * D_];
            float fb = vp[(size_t)(16 + p2) * D_];
            r.u[p2] = pk2(fa, fb);
        }
        return r.v;
    };

    v4f sum = {0.f, 0.f, 0.f, 0.f};
    for (int k0 = 0; k0 < S_; k0 += 32) {
        v4f a0 = {0.f, 0.f, 0.f, 0.f}, a1 = {0.f, 0.f, 0.f, 0.f};
        a0 = __builtin_amdgcn_mfma_f32_16x16x32_bf16(aq0, loadK(k0, 0), a0, 0, 0, 0);
        a0 = __builtin_amdgcn_mfma_f32_16x16x32_bf16(aq1, loadK(k0, 1), a0, 0, 0, 0);
        a1 = __builtin_amdgcn_mfma_f32_16x16x32_bf16(aq0, loadK(k0 + 16, 0), a1, 0, 0, 0);
        a1 = __builtin_amdgcn_mfma_f32_16x16x32_bf16(aq1, loadK(k0 + 16, 1), a1, 0, 0, 0);
        #pragma unroll
        for (int i = 0; i < 4; ++i) {
            u32 mw = loadM(i, k0);
            float e0 = ((mw >> n) & 1) ? __expf(a0[i]) : 0.f;
            float e1 = ((mw >> (n + 16)) & 1) ? __expf(a1[i]) : 0.f;
            sum[i] += e0 + e1;
        }
    }
    #pragma unroll
    for (int i = 0; i < 4; ++i) {
        float s = sum[i];
        s += __shfl_xor(s, 1, 64);
        s += __shfl_xor(s, 2, 64);
        s += __shfl_xor(s, 4, 64);
        s += __shfl_xor(s, 8, 64);
        sum[i] = 1.0f / s;
    }

    char* ldsw = (char*)&ldsbuf[w][0];
    float* pbase = P + ((size_t)bh * S_ + q0 + g * 4) * S_ + n;
    v4f o0 = {0.f, 0.f, 0.f, 0.f}, o1 = o0, o2 = o0, o3 = o0;

    for (int k0 = 0; k0 < S_; k0 += 32) {
        v4f a0 = {0.f, 0.f, 0.f, 0.f}, a1 = {0.f, 0.f, 0.f, 0.f};
        a0 = __builtin_amdgcn_mfma_f32_16x16x32_bf16(aq0, loadK(k0, 0), a0, 0, 0, 0);
        a0 = __builtin_amdgcn_mfma_f32_16x16x32_bf16(aq1, loadK(k0, 1), a0, 0, 0, 0);
        a1 = __builtin_amdgcn_mfma_f32_16x16x32_bf16(aq0, loadK(k0 + 16, 0), a1, 0, 0, 0);
        a1 = __builtin_amdgcn_mfma_f32_16x16x32_bf16(aq1, loadK(k0 + 16, 1), a1, 0, 0, 0);
        #pragma unroll
        for (int i = 0; i < 4; ++i) {
            u32 mw = loadM(i, k0);
            float p0 = ((mw >> n) & 1) ? __expf(a0[i]) * sum[i] : 0.f;
            float p1 = ((mw >> (n + 16)) & 1) ? __expf(a1[i]) * sum[i] : 0.f;
            pbase[(size_t)i * S_ + k0] = p0;
            pbase[(size_t)i * S_ + k0 + 16] = p1;
            *(u32*)(ldsw + (g * 4 + i) * 80 + n * 4) = pk2(p0, p1);
        }
        v8s ap = *(const v8s*)(ldsw + n * 80 + g * 16);
        o0 = __builtin_amdgcn_mfma_f32_16x16x32_bf16(ap, loadV(k0, 0), o0, 0, 0, 0);
        o1 = __builtin_amdgcn_mfma_f32_16x16x32_bf16(ap, loadV(k0, 1), o1, 0, 0, 0);
        o2 = __builtin_amdgcn_mfma_f32_16x16x32_bf16(ap, loadV(k0, 2), o2, 0, 0, 0);
        o3 = __builtin_amdgcn_mfma_f32_16x16x32_bf16(ap, loadV(k0, 3), o3, 0, 0, 0);
    }

    float* obase = out + ((size_t)bh * S_ + q0 + g * 4) * D_ + n;
    #pragma unroll
    for (int i = 0; i < 4; ++i) {
        obase[(size_t)i * D_]      = o0[i];
        obase[(size_t)i * D_ + 16] = o1[i];
        obase[(size_t)i * D_ + 32] = o2[i];
        obase[(size_t)i * D_ + 48] = o3[i];
    }
}

extern "C" void kernel_launch(void* const* d_in, const int* in_sizes, int n_in,
                              void* d_out, int out_size, void* d_ws, size_t ws_size,
                              hipStream_t stream)
{
    (void)in_sizes; (void)n_in; (void)out_size;
    const float* Q = (const float*)d_in[0];
    const float* K = (const float*)d_in[1];
    const float* V = (const float*)d_in[2];
    const int* mask = (const int*)d_in[3];
    float* out = (float*)d_out;
    float* P = out + (size_t)B_ * H_ * S_ * D_;

    const size_t kb_b = (size_t)B_ * H_ * S_ * D_ * 2;   // 8 MB  bf16 K
    const size_t vt_b = kb_b;                             // 8 MB  bf16 V^T
    const size_t mb_b = (size_t)B_ * S_ * S_ / 8;         // 1 MB  mask bits
    const size_t sb_b = (size_t)B_ * H_ * S_ * 4;         // 256 KB row sums

    if (ws_size >= kb_b + vt_b + mb_b + sb_b) {
        u16* Kb = (u16*)d_ws;
        u16* Vt = (u16*)((char*)d_ws + kb_b);
        u64* mb = (u64*)((char*)d_ws + kb_b + vt_b);
        float* sumbuf = (float*)((char*)d_ws + kb_b + vt_b + mb_b);

        const int out_n4 = B_ * H_ * S_ * D_ / 4;         // 1,048,576
        const int sb_n4  = B_ * H_ * S_ / 4;              // 16,384
        zero_k<<<(out_n4 + 255) / 256, 256, 0, stream>>>((float4*)out, out_n4);
        zero_k<<<(sb_n4 + 255) / 256, 256, 0, stream>>>((float4*)sumbuf, sb_n4);
        cvt_bf16_k<<<(B_ * H_ * S_ * D_) / (256 * 8), 256, 0, stream>>>(K, Kb);
        vtrans_k<<<dim3(S_ / 64, B_ * H_), 256, 0, stream>>>(V, Vt);
        mbits_k<<<(B_ * S_ * S_) / 256, 256, 0, stream>>>(mask, mb);

        sum_k<<<dim3((S_ / 64) * SPLIT1, H_, B_), 256, 0, stream>>>(Q, Kb, (const u32*)mb, sumbuf);
        main_k<<<dim3((S_ / 64) * SPLIT2, H_, B_), 256, 0, stream>>>(Q, Kb, Vt, (const u32*)mb, sumbuf, out, P);
    } else {
        attn_mono<<<dim3(S_ / 64, H_, B_), 256, 0, stream>>>(Q, K, V, mask, out, P);
    }
}